// Round 1
// baseline (154.230 us; speedup 1.0000x reference)
//
#include <hip/hip_runtime.h>
#include <stdint.h>

#define B 4096
#define D 2048
#define BK 128          // k-slab per K-step (fp8 elements; 128 B rows)
#define NITER (D / BK)  // 16
#define BM 128
#define BN 128

typedef unsigned long long ull;
typedef float f32x4 __attribute__((ext_vector_type(4)));

#define SENT_P 0x00000000FFFFFFFFull  // dist=0.0, ~idx -> "no positive seen"
#define SENT_N (~0ull)                // +inf      -> "no negative seen"

// ---------------- async global->LDS (16B per lane, wave-uniform LDS base) ----
__device__ __forceinline__ void async_copy16(const unsigned char* g, unsigned char* l) {
  __builtin_amdgcn_global_load_lds(
      (const __attribute__((address_space(1))) unsigned int*)g,
      (__attribute__((address_space(3))) unsigned int*)l,
      16, 0, 0);
}

// ---------------- fp32 -> fp8 e4m3 (OCP, RNE) + norms + sentinel init -------
__global__ void k_convert_sq(const float* __restrict__ emb,
                             unsigned char* __restrict__ embq,
                             float* __restrict__ sq,
                             float* __restrict__ rs,
                             ull* __restrict__ bp,
                             ull* __restrict__ bn) {
  const int row = blockIdx.x, t = threadIdx.x;
  const float4* src = (const float4*)(emb + (size_t)row * D);
  float4 v0 = src[2 * t], v1 = src[2 * t + 1];
  float s = v0.x * v0.x + v0.y * v0.y + v0.z * v0.z + v0.w * v0.w
          + v1.x * v1.x + v1.y * v1.y + v1.z * v1.z + v1.w * v1.w;
  float sm = v0.x + v0.y + v0.z + v0.w + v1.x + v1.y + v1.z + v1.w;

  unsigned w0 = __builtin_amdgcn_cvt_pk_fp8_f32(v0.x, v0.y, 0, false);
  w0 = __builtin_amdgcn_cvt_pk_fp8_f32(v0.z, v0.w, w0, true);
  unsigned w1 = __builtin_amdgcn_cvt_pk_fp8_f32(v1.x, v1.y, 0, false);
  w1 = __builtin_amdgcn_cvt_pk_fp8_f32(v1.z, v1.w, w1, true);
  uint2 o; o.x = w0; o.y = w1;
  ((uint2*)(embq + (size_t)row * D))[t] = o;

  for (int off = 32; off; off >>= 1) {
    s  += __shfl_down(s, off, 64);
    sm += __shfl_down(sm, off, 64);
  }
  __shared__ float ps[4], pm[4];
  int lane = t & 63, wave = t >> 6;
  if (lane == 0) { ps[wave] = s; pm[wave] = sm; }
  __syncthreads();
  if (t == 0) {
    sq[row] = ps[0] + ps[1] + ps[2] + ps[3];
    rs[row] = pm[0] + pm[1] + pm[2] + pm[3];
    bp[row] = SENT_P;
    bn[row] = SENT_N;
  }
}

// ---------------- fused symmetric fp8 GEMM + hard pos/neg selection ---------
// 128x128 tiles over the upper triangle of the 32x32 tile grid (528 blocks;
// diagonal blocks filtered to j > i in the epilogue). 4 waves as 2x2, each
// owning a 64x64 output (4x4 of 16x16x32 fp8 MFMA fragments -> 16 MFMA per
// 8 ds_read_b64 per k-slab, 2x the read amortization of the 64x128 tile).
// K-loop is a counted-vmcnt double-buffered pipeline: stage tile t+2 right
// after the read-done barrier, s_waitcnt vmcnt(8) (= loads/wave/tile, never
// 0 in steady state) so one full tile of loads stays in flight across the
// barrier and every load hides under a whole K-step of MFMA. Raw s_barrier
// (no implicit vmcnt(0) drain); setprio(1) around each MFMA cluster.
__launch_bounds__(256, 2)
__global__ void k_gemm_select(const unsigned char* __restrict__ embq,
                              const float* __restrict__ sq,
                              const int* __restrict__ labels,
                              ull* __restrict__ best_pos,
                              ull* __restrict__ best_neg) {
  __shared__ unsigned char ldsA0[BM * BK];  // 16 KB each, 64 KB total
  __shared__ unsigned char ldsB0[BN * BK];
  __shared__ unsigned char ldsA1[BM * BK];
  __shared__ unsigned char ldsB1[BN * BK];

  // linear bid -> (by, bx) with bx >= by over a 32x32 tile grid
  int rem = blockIdx.x, by = 0;
  while (rem >= 32 - by) { rem -= 32 - by; ++by; }
  const int bx = by + rem;

  const int tid  = threadIdx.x;
  const int lane = tid & 63;
  const int wave = tid >> 6;
  const int wm = wave >> 1, wn = wave & 1;
  const int q = lane >> 4, m15 = lane & 15;
  const int ibase = by * BM, jbase = bx * BN;

  // fragment read offsets (bytes) for slab s (k=s*32..s*32+31), row-group g:
  //   row = wbase + g*16 + m15 ; chunk = s*2 + (q>>1) ; slot = chunk ^ (row&7)
  //   byte = row*128 + slot*16 + (q&1)*8
  int aoff[4][4], boff[4][4];
#pragma unroll
  for (int s = 0; s < 4; ++s) {
#pragma unroll
    for (int g = 0; g < 4; ++g) {
      int ra = wm * 64 + g * 16 + m15;
      aoff[s][g] = ra * BK + (((s * 2 + (q >> 1)) ^ (ra & 7)) * 16) + (q & 1) * 8;
      int rb = wn * 64 + g * 16 + m15;
      boff[s][g] = rb * BK + (((s * 2 + (q >> 1)) ^ (rb & 7)) * 16) + (q & 1) * 8;
    }
  }

  // staging: 8 issues/wave per tile (4 A + 4 B), 8 rows x 1 KB per issue.
  // chunk at slot = chunk ^ (row&7) via pre-swizzled global source address
  // (global_load_lds dest must stay linear: base + lane*16).
  const int srow = lane >> 3;  // row within 8-row staging group
  const int slot = lane & 7;   // 16B slot within 128B row
  size_t agoff[4], bgoff[4];
  int ldst[4];
#pragma unroll
  for (int pp = 0; pp < 4; ++pp) {
    int r0  = wave * 32 + pp * 8;  // wave-uniform
    int row = r0 + srow;
    int gg  = (slot ^ (row & 7)) * 16;
    agoff[pp] = (size_t)(ibase + row) * D + gg;
    bgoff[pp] = (size_t)(jbase + row) * D + gg;
    ldst[pp]  = r0 * BK;
  }

  f32x4 acc[4][4];
  const f32x4 z = {0.f, 0.f, 0.f, 0.f};
#pragma unroll
  for (int a = 0; a < 4; ++a)
#pragma unroll
    for (int b = 0; b < 4; ++b) acc[a][b] = z;

  auto stage = [&](unsigned char* LA, unsigned char* LB, int kb) {
#pragma unroll
    for (int pp = 0; pp < 4; ++pp)
      async_copy16(embq + agoff[pp] + kb, &LA[ldst[pp]]);
#pragma unroll
    for (int pp = 0; pp < 4; ++pp)
      async_copy16(embq + bgoff[pp] + kb, &LB[ldst[pp]]);
  };

  auto compute = [&](const unsigned char* LA, const unsigned char* LB) {
#pragma unroll
    for (int s = 0; s < 4; ++s) {
      long af[4], bf[4];
#pragma unroll
      for (int g = 0; g < 4; ++g) af[g] = *(const long*)&LA[aoff[s][g]];
#pragma unroll
      for (int g = 0; g < 4; ++g) bf[g] = *(const long*)&LB[boff[s][g]];
      __builtin_amdgcn_s_setprio(1);
#pragma unroll
      for (int mi = 0; mi < 4; ++mi)
#pragma unroll
        for (int ni = 0; ni < 4; ++ni)
          acc[mi][ni] = __builtin_amdgcn_mfma_f32_16x16x32_fp8_fp8(
              af[mi], bf[ni], acc[mi][ni], 0, 0, 0);
      __builtin_amdgcn_s_setprio(0);
    }
  };

  // prologue: tiles 0 and 1 in flight; wait for tile 0 only (vmcnt 16->8)
  stage(ldsA0, ldsB0, 0);
  stage(ldsA1, ldsB1, BK);
  asm volatile("s_waitcnt vmcnt(8)" ::: "memory");
  __builtin_amdgcn_s_barrier();
  asm volatile("" ::: "memory");

  for (int t = 0; t < NITER; t += 2) {
    compute(ldsA0, ldsB0);
    asm volatile("" ::: "memory");
    __builtin_amdgcn_s_barrier();           // all waves done reading buf0
    if (t + 2 < NITER) {
      stage(ldsA0, ldsB0, (t + 2) * BK);    // 8 newest loads -> tile t+2
      asm volatile("s_waitcnt vmcnt(8)" ::: "memory");  // tile t+1 complete
    } else {
      asm volatile("s_waitcnt vmcnt(0)" ::: "memory");  // tail drain
    }
    __builtin_amdgcn_s_barrier();           // buf1 (tile t+1) ready chip-wide
    asm volatile("" ::: "memory");

    compute(ldsA1, ldsB1);
    if (t + 2 < NITER) {
      asm volatile("" ::: "memory");
      __builtin_amdgcn_s_barrier();         // all waves done reading buf1
      if (t + 3 < NITER) {
        stage(ldsA1, ldsB1, (t + 3) * BK);
        asm volatile("s_waitcnt vmcnt(8)" ::: "memory");  // tile t+2 complete
      } else {
        asm volatile("s_waitcnt vmcnt(0)" ::: "memory");
      }
      __builtin_amdgcn_s_barrier();         // buf0 (tile t+2) ready
      asm volatile("" ::: "memory");
    }
  }

  // ---- epilogue ----
  float sqj[4];
  int labj[4];
#pragma unroll
  for (int ni = 0; ni < 4; ++ni) {
    int jj = jbase + wn * 64 + ni * 16 + m15;
    sqj[ni] = sq[jj];
    labj[ni] = labels[jj];
  }

  ull colBp[4], colBn[4];
#pragma unroll
  for (int ni = 0; ni < 4; ++ni) { colBp[ni] = SENT_P; colBn[ni] = SENT_N; }

#pragma unroll
  for (int mi = 0; mi < 4; ++mi) {
#pragma unroll
    for (int r = 0; r < 4; ++r) {
      const int i = ibase + wm * 64 + mi * 16 + q * 4 + r;  // C/D row=(lane>>4)*4+r
      const float si = sq[i];
      const int li = labels[i];
      ull bp = SENT_P;
      ull bn = SENT_N;
#pragma unroll
      for (int ni = 0; ni < 4; ++ni) {
        int jj = jbase + wn * 64 + ni * 16 + m15;  // C/D col=lane&15
        if (jj > i) {                              // strict upper triangle only
          float dot = acc[mi][ni][r];
          float d2 = si + sqj[ni] - 2.0f * dot;
          float dist = sqrtf(fmaxf(d2, 0.0f));
          ull pv = ((ull)__float_as_uint(dist)) << 32;
          if (labj[ni] == li) {
            ull cr = pv | (unsigned)(~jj);  // max -> smallest idx wins ties
            bp = bp > cr ? bp : cr;
            ull cc = pv | (unsigned)(~i);
            colBp[ni] = colBp[ni] > cc ? colBp[ni] : cc;
          } else {
            ull cr = pv | (unsigned)jj;     // min -> smallest idx wins ties
            bn = bn < cr ? bn : cr;
            ull cc = pv | (unsigned)i;
            colBn[ni] = colBn[ni] < cc ? colBn[ni] : cc;
          }
        }
      }
      // row-i reduction across the 16 column lanes (m15 bits)
#pragma unroll
      for (int off = 1; off <= 8; off <<= 1) {
        ull op = __shfl_xor(bp, off, 64);
        ull on = __shfl_xor(bn, off, 64);
        bp = bp > op ? bp : op;
        bn = bn < on ? bn : on;
      }
      if (m15 == 0) {
        if (bp != SENT_P) atomicMax(&best_pos[i], bp);
        if (bn != SENT_N) atomicMin(&best_neg[i], bn);
      }
    }
  }

  // col-j reduction across the 4 q lane-groups
#pragma unroll
  for (int ni = 0; ni < 4; ++ni) {
    ull cp = colBp[ni], cn = colBn[ni];
#pragma unroll
    for (int off = 16; off <= 32; off <<= 1) {
      ull op = __shfl_xor(cp, off, 64);
      ull on = __shfl_xor(cn, off, 64);
      cp = cp > op ? cp : op;
      cn = cn < on ? cn : on;
    }
    if (q == 0) {
      int j = jbase + wn * 64 + ni * 16 + m15;
      if (cp != SENT_P) atomicMax(&best_pos[j], cp);
      if (cn != SENT_N) atomicMin(&best_neg[j], cn);
    }
  }
}

// ---------------- loss + finalize in one single-block kernel ----------------
__global__ void k_loss_final(const ull* __restrict__ best_pos,
                             const ull* __restrict__ best_neg,
                             const float* __restrict__ rs,
                             float* __restrict__ out) {
  float per = 0.0f;
  int v = 0;
  for (int i = threadIdx.x; i < B; i += 1024) {
    ull bp = best_pos[i], bn = best_neg[i];
    if (bp != SENT_P && bn != SENT_N) {
      unsigned pRaw = ~(unsigned)bp;
      unsigned nRaw = (unsigned)bn;
      int pi = pRaw < (unsigned)B ? (int)pRaw : 0;
      int ni = nRaw < (unsigned)B ? (int)nRaw : 0;
      float distp = __uint_as_float((unsigned)(bp >> 32));
      float distn = __uint_as_float((unsigned)(bn >> 32));
      float ri = rs[i];
      const float e = 1e-6f, de2 = (float)D * 1e-12f;
      float dp2 = distp * distp + 2.0f * e * (ri - rs[pi]) + de2;
      float dn2 = distn * distn + 2.0f * e * (ri - rs[ni]) + de2;
      float dp = sqrtf(fmaxf(dp2, 0.0f));
      float dn = sqrtf(fmaxf(dn2, 0.0f));
      per += fmaxf(dp - dn + 0.3f, 0.0f);
      v += 1;
    }
  }
  for (int off = 32; off; off >>= 1) {
    per += __shfl_down(per, off, 64);
    v   += __shfl_down(v, off, 64);
  }
  __shared__ float pps[16];
  __shared__ int pvs[16];
  int lane = threadIdx.x & 63, wave = threadIdx.x >> 6;
  if (lane == 0) { pps[wave] = per; pvs[wave] = v; }
  __syncthreads();
  if (threadIdx.x == 0) {
    float t = 0.f;
    int cv = 0;
#pragma unroll
    for (int w = 0; w < 16; ++w) { t += pps[w]; cv += pvs[w]; }
    out[0] = cv > 0 ? t / (float)cv : 0.0f;
  }
}

// ---------------- launch -----------------------------------------------------
extern "C" void kernel_launch(void* const* d_in, const int* in_sizes, int n_in,
                              void* d_out, int out_size, void* d_ws, size_t ws_size,
                              hipStream_t stream) {
  const float* emb = (const float*)d_in[0];
  const int* labels = (const int*)d_in[1];
  float* out = (float*)d_out;
  char* ws = (char*)d_ws;

  const size_t off_embq = 0;
  const size_t off_sq   = off_embq + (size_t)B * D;       // 8 MiB
  const size_t off_rs   = off_sq + (size_t)B * 4;
  const size_t off_bp   = off_rs + (size_t)B * 4;
  const size_t off_bn   = off_bp + (size_t)B * 8;

  unsigned char* embq = (unsigned char*)(ws + off_embq);
  float* sq   = (float*)(ws + off_sq);
  float* rs   = (float*)(ws + off_rs);
  ull* bp     = (ull*)(ws + off_bp);
  ull* bn     = (ull*)(ws + off_bn);

  hipLaunchKernelGGL(k_convert_sq, dim3(B), dim3(256), 0, stream,
                     emb, embq, sq, rs, bp, bn);
  hipLaunchKernelGGL(k_gemm_select, dim3(528), dim3(256), 0, stream,
                     embq, sq, labels, bp, bn);
  hipLaunchKernelGGL(k_loss_final, dim3(1), dim3(1024), 0, stream,
                     bp, bn, rs, out);
}

// Round 2
// 134.488 us; speedup vs baseline: 1.1468x; 1.1468x over previous
//
#include <hip/hip_runtime.h>
#include <stdint.h>

#define B 4096
#define D 2048
#define BK 128          // k-slab per K-step (fp8 elements; 128 B rows)
#define NITER (D / BK)  // 16
#define BM 64
#define BN 128

typedef unsigned long long ull;
typedef float f32x4 __attribute__((ext_vector_type(4)));

#define SENT_P 0x00000000FFFFFFFFull  // dist=0.0, ~idx -> "no positive seen"
#define SENT_N (~0ull)                // +inf      -> "no negative seen"

// ---------------- async global->LDS (16B per lane, wave-uniform LDS base) ----
__device__ __forceinline__ void async_copy16(const unsigned char* g, unsigned char* l) {
  __builtin_amdgcn_global_load_lds(
      (const __attribute__((address_space(1))) unsigned int*)g,
      (__attribute__((address_space(3))) unsigned int*)l,
      16, 0, 0);
}

// ---------------- fp32 -> fp8 e4m3 (OCP, RNE) + norms + sentinel init -------
__global__ void k_convert_sq(const float* __restrict__ emb,
                             unsigned char* __restrict__ embq,
                             float* __restrict__ sq,
                             float* __restrict__ rs,
                             ull* __restrict__ bp,
                             ull* __restrict__ bn) {
  const int row = blockIdx.x, t = threadIdx.x;
  const float4* src = (const float4*)(emb + (size_t)row * D);
  float4 v0 = src[2 * t], v1 = src[2 * t + 1];
  float s = v0.x * v0.x + v0.y * v0.y + v0.z * v0.z + v0.w * v0.w
          + v1.x * v1.x + v1.y * v1.y + v1.z * v1.z + v1.w * v1.w;
  float sm = v0.x + v0.y + v0.z + v0.w + v1.x + v1.y + v1.z + v1.w;

  unsigned w0 = __builtin_amdgcn_cvt_pk_fp8_f32(v0.x, v0.y, 0, false);
  w0 = __builtin_amdgcn_cvt_pk_fp8_f32(v0.z, v0.w, w0, true);
  unsigned w1 = __builtin_amdgcn_cvt_pk_fp8_f32(v1.x, v1.y, 0, false);
  w1 = __builtin_amdgcn_cvt_pk_fp8_f32(v1.z, v1.w, w1, true);
  uint2 o; o.x = w0; o.y = w1;
  ((uint2*)(embq + (size_t)row * D))[t] = o;

  for (int off = 32; off; off >>= 1) {
    s  += __shfl_down(s, off, 64);
    sm += __shfl_down(sm, off, 64);
  }
  __shared__ float ps[4], pm[4];
  int lane = t & 63, wave = t >> 6;
  if (lane == 0) { ps[wave] = s; pm[wave] = sm; }
  __syncthreads();
  if (t == 0) {
    sq[row] = ps[0] + ps[1] + ps[2] + ps[3];
    rs[row] = pm[0] + pm[1] + pm[2] + pm[3];
    bp[row] = SENT_P;
    bn[row] = SENT_N;
  }
}

// ---------------- fused symmetric fp8 GEMM + hard pos/neg selection ---------
// 64x128 tiles over the strict upper triangle (1056 blocks, R4's sequential
// triangular decode — the proven round-0 mapping) COMBINED with the
// counted-vmcnt double-buffered K-pipeline from round 1:
//   - LDS = 2 x (64+128) x 128 B = 48 KB -> 3 blocks/CU resident (TLP back:
//     12 waves/CU vs round-1's 8; round-1's 64 KB capped residency at 2 and
//     lost 1.5x to 528-block quantization).
//   - stage tile t+2 right after the read-done barrier, s_waitcnt vmcnt(6)
//     (= 6 loads/wave/tile, never 0 in steady state) so a full tile of
//     loads stays in flight across barriers.
//   - bijective XCD swizzle (1056 = 8*132): consecutive logical tiles share
//     the A row-panel (~256-384 KB) -> per-XCD L2-resident staging.
__launch_bounds__(256, 3)
__global__ void k_gemm_select(const unsigned char* __restrict__ embq,
                              const float* __restrict__ sq,
                              const int* __restrict__ labels,
                              ull* __restrict__ best_pos,
                              ull* __restrict__ best_neg) {
  __shared__ unsigned char ldsA0[BM * BK];  // 8 KB
  __shared__ unsigned char ldsB0[BN * BK];  // 16 KB
  __shared__ unsigned char ldsA1[BM * BK];  // 8 KB
  __shared__ unsigned char ldsB1[BN * BK];  // 16 KB  (48 KB total)

  // XCD-aware remap: hardware bid -> logical tile id, chunked per XCD
  const int lid = (blockIdx.x & 7) * 132 + (blockIdx.x >> 3);

  // linear lid -> (by in [0,64), bx in [0,32)) with bx*128+127 > by*64
  int rem = lid, p = 0;
  while (rem >= 2 * (32 - p)) { rem -= 2 * (32 - p); ++p; }
  int by = 2 * p;
  int c = 32 - p;
  if (rem >= c) { by += 1; rem -= c; }
  const int bx = p + rem;

  const int tid  = threadIdx.x;
  const int lane = tid & 63;
  const int wave = tid >> 6;
  const int wm = wave >> 1, wn = wave & 1;
  const int q = lane >> 4, m15 = lane & 15;
  const int ibase = by * BM, jbase = bx * BN;

  // fragment read offsets (bytes) for slab s (k=s*32..s*32+31), row-group g:
  //   row = wbase + g*16 + m15 ; chunk = s*2 + (q>>1) ; slot = chunk ^ (row&7)
  //   byte = row*128 + slot*16 + (q&1)*8
  int aoff[4][2], boff[4][4];
#pragma unroll
  for (int s = 0; s < 4; ++s) {
#pragma unroll
    for (int g = 0; g < 2; ++g) {
      int ra = wm * 32 + g * 16 + m15;
      aoff[s][g] = ra * BK + (((s * 2 + (q >> 1)) ^ (ra & 7)) * 16) + (q & 1) * 8;
    }
#pragma unroll
    for (int g = 0; g < 4; ++g) {
      int rb = wn * 64 + g * 16 + m15;
      boff[s][g] = rb * BK + (((s * 2 + (q >> 1)) ^ (rb & 7)) * 16) + (q & 1) * 8;
    }
  }

  // staging: 6 issues/wave per tile (2 A + 4 B), 8 rows x 1 KB per issue.
  // chunk at slot = chunk ^ (row&7) via pre-swizzled global source address
  // (global_load_lds dest must stay linear: base + lane*16).
  const int srow = lane >> 3;  // row within 8-row staging group
  const int slot = lane & 7;   // 16B slot within 128B row
  size_t agoff[2], bgoff[4];
  int lasta[2], lastb[4];
#pragma unroll
  for (int pp = 0; pp < 2; ++pp) {
    int r0  = wave * 16 + pp * 8;  // wave-uniform
    int row = r0 + srow;
    int gg  = (slot ^ (row & 7)) * 16;
    agoff[pp] = (size_t)(ibase + row) * D + gg;
    lasta[pp] = r0 * BK;
  }
#pragma unroll
  for (int pp = 0; pp < 4; ++pp) {
    int r0  = wave * 32 + pp * 8;  // wave-uniform
    int row = r0 + srow;
    int gg  = (slot ^ (row & 7)) * 16;
    bgoff[pp] = (size_t)(jbase + row) * D + gg;
    lastb[pp] = r0 * BK;
  }

  f32x4 acc[2][4];
  const f32x4 z = {0.f, 0.f, 0.f, 0.f};
#pragma unroll
  for (int a = 0; a < 2; ++a)
#pragma unroll
    for (int b = 0; b < 4; ++b) acc[a][b] = z;

  auto stage = [&](unsigned char* LA, unsigned char* LB, int kb) {
#pragma unroll
    for (int pp = 0; pp < 2; ++pp)
      async_copy16(embq + agoff[pp] + kb, &LA[lasta[pp]]);
#pragma unroll
    for (int pp = 0; pp < 4; ++pp)
      async_copy16(embq + bgoff[pp] + kb, &LB[lastb[pp]]);
  };

  auto compute = [&](const unsigned char* LA, const unsigned char* LB) {
#pragma unroll
    for (int s = 0; s < 4; ++s) {
      long af[2], bf[4];
#pragma unroll
      for (int g = 0; g < 2; ++g) af[g] = *(const long*)&LA[aoff[s][g]];
#pragma unroll
      for (int g = 0; g < 4; ++g) bf[g] = *(const long*)&LB[boff[s][g]];
      __builtin_amdgcn_s_setprio(1);
#pragma unroll
      for (int mi = 0; mi < 2; ++mi)
#pragma unroll
        for (int ni = 0; ni < 4; ++ni)
          acc[mi][ni] = __builtin_amdgcn_mfma_f32_16x16x32_fp8_fp8(
              af[mi], bf[ni], acc[mi][ni], 0, 0, 0);
      __builtin_amdgcn_s_setprio(0);
    }
  };

  // prologue: tiles 0 and 1 in flight; wait for tile 0 only (vmcnt 12->6)
  stage(ldsA0, ldsB0, 0);
  stage(ldsA1, ldsB1, BK);
  asm volatile("s_waitcnt vmcnt(6)" ::: "memory");
  __builtin_amdgcn_s_barrier();
  asm volatile("" ::: "memory");

  for (int t = 0; t < NITER; t += 2) {
    compute(ldsA0, ldsB0);
    asm volatile("" ::: "memory");
    __builtin_amdgcn_s_barrier();           // all waves done reading buf0
    if (t + 2 < NITER) {
      stage(ldsA0, ldsB0, (t + 2) * BK);    // 6 newest loads -> tile t+2
      asm volatile("s_waitcnt vmcnt(6)" ::: "memory");  // tile t+1 complete
    } else {
      asm volatile("s_waitcnt vmcnt(0)" ::: "memory");  // tail drain
    }
    __builtin_amdgcn_s_barrier();           // buf1 (tile t+1) ready
    asm volatile("" ::: "memory");

    compute(ldsA1, ldsB1);
    if (t + 2 < NITER) {
      asm volatile("" ::: "memory");
      __builtin_amdgcn_s_barrier();         // all waves done reading buf1
      if (t + 3 < NITER) {
        stage(ldsA1, ldsB1, (t + 3) * BK);
        asm volatile("s_waitcnt vmcnt(6)" ::: "memory");  // tile t+2 complete
      } else {
        asm volatile("s_waitcnt vmcnt(0)" ::: "memory");
      }
      __builtin_amdgcn_s_barrier();         // buf0 (tile t+2) ready
      asm volatile("" ::: "memory");
    }
  }

  // ---- epilogue ----
  float sqj[4];
  int labj[4];
#pragma unroll
  for (int ni = 0; ni < 4; ++ni) {
    int jj = jbase + wn * 64 + ni * 16 + m15;
    sqj[ni] = sq[jj];
    labj[ni] = labels[jj];
  }

  ull colBp[4], colBn[4];
#pragma unroll
  for (int ni = 0; ni < 4; ++ni) { colBp[ni] = SENT_P; colBn[ni] = SENT_N; }

#pragma unroll
  for (int mi = 0; mi < 2; ++mi) {
#pragma unroll
    for (int r = 0; r < 4; ++r) {
      const int i = ibase + wm * 32 + mi * 16 + q * 4 + r;  // C/D row=(lane>>4)*4+r
      const float si = sq[i];
      const int li = labels[i];
      ull bp = SENT_P;
      ull bn = SENT_N;
#pragma unroll
      for (int ni = 0; ni < 4; ++ni) {
        int jj = jbase + wn * 64 + ni * 16 + m15;  // C/D col=lane&15
        if (jj > i) {                              // strict upper triangle only
          float dot = acc[mi][ni][r];
          float d2 = si + sqj[ni] - 2.0f * dot;
          float dist = sqrtf(fmaxf(d2, 0.0f));
          ull pv = ((ull)__float_as_uint(dist)) << 32;
          if (labj[ni] == li) {
            ull cr = pv | (unsigned)(~jj);  // max -> smallest idx wins ties
            bp = bp > cr ? bp : cr;
            ull cc = pv | (unsigned)(~i);
            colBp[ni] = colBp[ni] > cc ? colBp[ni] : cc;
          } else {
            ull cr = pv | (unsigned)jj;     // min -> smallest idx wins ties
            bn = bn < cr ? bn : cr;
            ull cc = pv | (unsigned)i;
            colBn[ni] = colBn[ni] < cc ? colBn[ni] : cc;
          }
        }
      }
      // row-i reduction across the 16 column lanes (m15 bits)
#pragma unroll
      for (int off = 1; off <= 8; off <<= 1) {
        ull op = __shfl_xor(bp, off, 64);
        ull on = __shfl_xor(bn, off, 64);
        bp = bp > op ? bp : op;
        bn = bn < on ? bn : on;
      }
      if (m15 == 0) {
        if (bp != SENT_P) atomicMax(&best_pos[i], bp);
        if (bn != SENT_N) atomicMin(&best_neg[i], bn);
      }
    }
  }

  // col-j reduction across the 4 q lane-groups
#pragma unroll
  for (int ni = 0; ni < 4; ++ni) {
    ull cp = colBp[ni], cn = colBn[ni];
#pragma unroll
    for (int off = 16; off <= 32; off <<= 1) {
      ull op = __shfl_xor(cp, off, 64);
      ull on = __shfl_xor(cn, off, 64);
      cp = cp > op ? cp : op;
      cn = cn < on ? cn : on;
    }
    if (q == 0) {
      int j = jbase + wn * 64 + ni * 16 + m15;
      if (cp != SENT_P) atomicMax(&best_pos[j], cp);
      if (cn != SENT_N) atomicMin(&best_neg[j], cn);
    }
  }
}

// ---------------- loss + finalize in one single-block kernel ----------------
__global__ void k_loss_final(const ull* __restrict__ best_pos,
                             const ull* __restrict__ best_neg,
                             const float* __restrict__ rs,
                             float* __restrict__ out) {
  float per = 0.0f;
  int v = 0;
  for (int i = threadIdx.x; i < B; i += 1024) {
    ull bp = best_pos[i], bn = best_neg[i];
    if (bp != SENT_P && bn != SENT_N) {
      unsigned pRaw = ~(unsigned)bp;
      unsigned nRaw = (unsigned)bn;
      int pi = pRaw < (unsigned)B ? (int)pRaw : 0;
      int ni = nRaw < (unsigned)B ? (int)nRaw : 0;
      float distp = __uint_as_float((unsigned)(bp >> 32));
      float distn = __uint_as_float((unsigned)(bn >> 32));
      float ri = rs[i];
      const float e = 1e-6f, de2 = (float)D * 1e-12f;
      float dp2 = distp * distp + 2.0f * e * (ri - rs[pi]) + de2;
      float dn2 = distn * distn + 2.0f * e * (ri - rs[ni]) + de2;
      float dp = sqrtf(fmaxf(dp2, 0.0f));
      float dn = sqrtf(fmaxf(dn2, 0.0f));
      per += fmaxf(dp - dn + 0.3f, 0.0f);
      v += 1;
    }
  }
  for (int off = 32; off; off >>= 1) {
    per += __shfl_down(per, off, 64);
    v   += __shfl_down(v, off, 64);
  }
  __shared__ float pps[16];
  __shared__ int pvs[16];
  int lane = threadIdx.x & 63, wave = threadIdx.x >> 6;
  if (lane == 0) { pps[wave] = per; pvs[wave] = v; }
  __syncthreads();
  if (threadIdx.x == 0) {
    float t = 0.f;
    int cv = 0;
#pragma unroll
    for (int w = 0; w < 16; ++w) { t += pps[w]; cv += pvs[w]; }
    out[0] = cv > 0 ? t / (float)cv : 0.0f;
  }
}

// ---------------- launch -----------------------------------------------------
extern "C" void kernel_launch(void* const* d_in, const int* in_sizes, int n_in,
                              void* d_out, int out_size, void* d_ws, size_t ws_size,
                              hipStream_t stream) {
  const float* emb = (const float*)d_in[0];
  const int* labels = (const int*)d_in[1];
  float* out = (float*)d_out;
  char* ws = (char*)d_ws;

  const size_t off_embq = 0;
  const size_t off_sq   = off_embq + (size_t)B * D;       // 8 MiB
  const size_t off_rs   = off_sq + (size_t)B * 4;
  const size_t off_bp   = off_rs + (size_t)B * 4;
  const size_t off_bn   = off_bp + (size_t)B * 8;

  unsigned char* embq = (unsigned char*)(ws + off_embq);
  float* sq   = (float*)(ws + off_sq);
  float* rs   = (float*)(ws + off_rs);
  ull* bp     = (ull*)(ws + off_bp);
  ull* bn     = (ull*)(ws + off_bn);

  hipLaunchKernelGGL(k_convert_sq, dim3(B), dim3(256), 0, stream,
                     emb, embq, sq, rs, bp, bn);
  hipLaunchKernelGGL(k_gemm_select, dim3(1056), dim3(256), 0, stream,
                     embq, sq, labels, bp, bn);
  hipLaunchKernelGGL(k_loss_final, dim3(1), dim3(1024), 0, stream,
                     bp, bn, rs, out);
}

// Round 3
// 123.720 us; speedup vs baseline: 1.2466x; 1.0870x over previous
//
#include <hip/hip_runtime.h>
#include <stdint.h>

#define B 4096
#define D 2048
#define BK 128          // k-slab per K-step (fp8 elements; 128 B rows)
#define NITER (D / BK)  // 16
#define BM 64
#define BN 128

typedef unsigned long long ull;
typedef float f32x4 __attribute__((ext_vector_type(4)));
typedef long v2l __attribute__((ext_vector_type(2)));  // 16 B, 16-B aligned

#define SENT_P 0x00000000FFFFFFFFull  // dist=0.0, ~idx -> "no positive seen"
#define SENT_N (~0ull)                // +inf      -> "no negative seen"

// ---------------- async global->LDS (16B per lane, wave-uniform LDS base) ----
__device__ __forceinline__ void async_copy16(const unsigned char* g, unsigned char* l) {
  __builtin_amdgcn_global_load_lds(
      (const __attribute__((address_space(1))) unsigned int*)g,
      (__attribute__((address_space(3))) unsigned int*)l,
      16, 0, 0);
}

// ---------------- fp32 -> fp8 e4m3 (OCP, RNE) + norms + sentinel init -------
// embq is written in a k-PERMUTED layout (dot products are invariant under a
// uniform k-permutation of both operands). Within each 128 B K-step segment:
//   orig k = s*32 + qp*8 + b  (s=slab 0..3, qp=MFMA lane-group 0..3, b=0..7)
//   stored at pos = qp*32 + s*8 + b   ("q-major")
// so one 16 B chunk c = qp*2 + (s>>1) holds a lane-group's fragments for TWO
// consecutive slabs -> the GEMM reads it with a single ds_read_b128 whose
// 64-lane bank pattern covers all 32 banks (free 2-way) instead of the
// irreducible 2x 16-bank conflict of 8 B reads.
__global__ void k_convert_sq(const float* __restrict__ emb,
                             unsigned char* __restrict__ embq,
                             float* __restrict__ sq,
                             float* __restrict__ rs,
                             ull* __restrict__ bp,
                             ull* __restrict__ bn) {
  const int row = blockIdx.x, t = threadIdx.x;
  const float4* src = (const float4*)(emb + (size_t)row * D);
  float4 v0 = src[2 * t], v1 = src[2 * t + 1];
  float s = v0.x * v0.x + v0.y * v0.y + v0.z * v0.z + v0.w * v0.w
          + v1.x * v1.x + v1.y * v1.y + v1.z * v1.z + v1.w * v1.w;
  float sm = v0.x + v0.y + v0.z + v0.w + v1.x + v1.y + v1.z + v1.w;

  unsigned w0 = __builtin_amdgcn_cvt_pk_fp8_f32(v0.x, v0.y, 0, false);
  w0 = __builtin_amdgcn_cvt_pk_fp8_f32(v0.z, v0.w, w0, true);
  unsigned w1 = __builtin_amdgcn_cvt_pk_fp8_f32(v1.x, v1.y, 0, false);
  w1 = __builtin_amdgcn_cvt_pk_fp8_f32(v1.z, v1.w, w1, true);
  uint2 o; o.x = w0; o.y = w1;
  // thread t holds orig k in [8t, 8t+8): kb = t>>4, s = (t>>2)&3, qp = t&3
  const int pos = ((t >> 4) << 7) | ((t & 3) << 5) | (((t >> 2) & 3) << 3);
  *(uint2*)(embq + (size_t)row * D + pos) = o;

  for (int off = 32; off; off >>= 1) {
    s  += __shfl_down(s, off, 64);
    sm += __shfl_down(sm, off, 64);
  }
  __shared__ float ps[4], pm[4];
  int lane = t & 63, wave = t >> 6;
  if (lane == 0) { ps[wave] = s; pm[wave] = sm; }
  __syncthreads();
  if (t == 0) {
    sq[row] = ps[0] + ps[1] + ps[2] + ps[3];
    rs[row] = pm[0] + pm[1] + pm[2] + pm[3];
    bp[row] = SENT_P;
    bn[row] = SENT_N;
  }
}

// ---------------- fused symmetric fp8 GEMM + hard pos/neg selection ---------
// Round-0 proven structure (64x128 tiles over the strict upper triangle,
// 1056 blocks = 4.1/CU balance, single-buffered 24 KB LDS, __syncthreads
// drain each K-step, 4+ blocks/CU TLP hides staging latency). The one change
// vs round 0: the q-major k-permuted embq layout lets each fragment fetch be
// a 16 B ds_read_b128 delivering two slabs' fragments at the conflict-free
// LDS floor (12 b128/wave/K-step vs 24 2x-conflicted b64) — the LDS pipe was
// the largest per-CU load (26 us vs MFMA 17 us) and runs at 2x its floor.
__launch_bounds__(256, 4)
__global__ void k_gemm_select(const unsigned char* __restrict__ embq,
                              const float* __restrict__ sq,
                              const int* __restrict__ labels,
                              ull* __restrict__ best_pos,
                              ull* __restrict__ best_neg) {
  __shared__ __align__(16) unsigned char ldsA[BM * BK];  // 8 KB
  __shared__ __align__(16) unsigned char ldsB[BN * BK];  // 16 KB

  // linear bid -> (by in [0,64), bx in [0,32)) with bx*128+127 > by*64
  int rem = blockIdx.x, p = 0;
  while (rem >= 2 * (32 - p)) { rem -= 2 * (32 - p); ++p; }
  int by = 2 * p;
  int c = 32 - p;
  if (rem >= c) { by += 1; rem -= c; }
  const int bx = p + rem;

  const int tid  = threadIdx.x;
  const int lane = tid & 63;
  const int wave = tid >> 6;
  const int wm = wave >> 1, wn = wave & 1;
  const int q = lane >> 4, m15 = lane & 15;
  const int ibase = by * BM, jbase = bx * BN;

  // b128 fragment read offsets for slab-pair sh (slabs 2sh, 2sh+1), group g:
  //   row = wbase + g*16 + m15 ; chunk = q*2 + sh ; slot = chunk ^ (row&7)
  //   byte = row*128 + slot*16   (16-B aligned; [0,8)=slab 2sh, [8,16)=2sh+1)
  int aoff[2][2], boff[2][4];
#pragma unroll
  for (int sh = 0; sh < 2; ++sh) {
#pragma unroll
    for (int g = 0; g < 2; ++g) {
      int ra = wm * 32 + g * 16 + m15;
      aoff[sh][g] = ra * BK + (((q * 2 + sh) ^ (ra & 7)) * 16);
    }
#pragma unroll
    for (int g = 0; g < 4; ++g) {
      int rb = wn * 64 + g * 16 + m15;
      boff[sh][g] = rb * BK + (((q * 2 + sh) ^ (rb & 7)) * 16);
    }
  }

  // staging: 6 issues/wave per K-step (2 A + 4 B), 8 rows x 1 KB per issue.
  // LDS dest linear (base + lane*16); global source pre-swizzled so LDS slot
  // `slot` holds global chunk slot^(row&7)  (XOR involution matches reads).
  const int srow = lane >> 3;  // row within 8-row staging group
  const int slot = lane & 7;   // 16B slot within 128B row
  size_t agoff[2], bgoff[4];
  int lasta[2], lastb[4];
#pragma unroll
  for (int pp = 0; pp < 2; ++pp) {
    int r0  = wave * 16 + pp * 8;  // wave-uniform
    int row = r0 + srow;
    agoff[pp] = (size_t)(ibase + row) * D + (slot ^ (row & 7)) * 16;
    lasta[pp] = r0 * BK;
  }
#pragma unroll
  for (int pp = 0; pp < 4; ++pp) {
    int r0  = wave * 32 + pp * 8;  // wave-uniform
    int row = r0 + srow;
    bgoff[pp] = (size_t)(jbase + row) * D + (slot ^ (row & 7)) * 16;
    lastb[pp] = r0 * BK;
  }

  f32x4 acc[2][4];
  const f32x4 z = {0.f, 0.f, 0.f, 0.f};
#pragma unroll
  for (int a = 0; a < 2; ++a)
#pragma unroll
    for (int b = 0; b < 4; ++b) acc[a][b] = z;

  for (int kb = 0; kb < D; kb += BK) {
    __syncthreads();
#pragma unroll
    for (int pp = 0; pp < 2; ++pp)
      async_copy16(embq + agoff[pp] + kb, &ldsA[lasta[pp]]);
#pragma unroll
    for (int pp = 0; pp < 4; ++pp)
      async_copy16(embq + bgoff[pp] + kb, &ldsB[lastb[pp]]);
    __syncthreads();  // compiler emits vmcnt(0) drain before barrier

#pragma unroll
    for (int sh = 0; sh < 2; ++sh) {
      v2l af[2], bf[4];
#pragma unroll
      for (int g = 0; g < 2; ++g) af[g] = *(const v2l*)&ldsA[aoff[sh][g]];
#pragma unroll
      for (int g = 0; g < 4; ++g) bf[g] = *(const v2l*)&ldsB[boff[sh][g]];
#pragma unroll
      for (int mi = 0; mi < 2; ++mi)
#pragma unroll
        for (int ni = 0; ni < 4; ++ni)
          acc[mi][ni] = __builtin_amdgcn_mfma_f32_16x16x32_fp8_fp8(
              af[mi][0], bf[ni][0], acc[mi][ni], 0, 0, 0);
#pragma unroll
      for (int mi = 0; mi < 2; ++mi)
#pragma unroll
        for (int ni = 0; ni < 4; ++ni)
          acc[mi][ni] = __builtin_amdgcn_mfma_f32_16x16x32_fp8_fp8(
              af[mi][1], bf[ni][1], acc[mi][ni], 0, 0, 0);
    }
  }

  // ---- epilogue ----
  float sqj[4];
  int labj[4];
#pragma unroll
  for (int ni = 0; ni < 4; ++ni) {
    int jj = jbase + wn * 64 + ni * 16 + m15;
    sqj[ni] = sq[jj];
    labj[ni] = labels[jj];
  }

  ull colBp[4], colBn[4];
#pragma unroll
  for (int ni = 0; ni < 4; ++ni) { colBp[ni] = SENT_P; colBn[ni] = SENT_N; }

#pragma unroll
  for (int mi = 0; mi < 2; ++mi) {
#pragma unroll
    for (int r = 0; r < 4; ++r) {
      const int i = ibase + wm * 32 + mi * 16 + q * 4 + r;  // C/D row=(lane>>4)*4+r
      const float si = sq[i];
      const int li = labels[i];
      ull bp = SENT_P;
      ull bn = SENT_N;
#pragma unroll
      for (int ni = 0; ni < 4; ++ni) {
        int jj = jbase + wn * 64 + ni * 16 + m15;  // C/D col=lane&15
        if (jj > i) {                              // strict upper triangle only
          float dot = acc[mi][ni][r];
          float d2 = si + sqj[ni] - 2.0f * dot;
          float dist = sqrtf(fmaxf(d2, 0.0f));
          ull pv = ((ull)__float_as_uint(dist)) << 32;
          if (labj[ni] == li) {
            ull cr = pv | (unsigned)(~jj);  // max -> smallest idx wins ties
            bp = bp > cr ? bp : cr;
            ull cc = pv | (unsigned)(~i);
            colBp[ni] = colBp[ni] > cc ? colBp[ni] : cc;
          } else {
            ull cr = pv | (unsigned)jj;     // min -> smallest idx wins ties
            bn = bn < cr ? bn : cr;
            ull cc = pv | (unsigned)i;
            colBn[ni] = colBn[ni] < cc ? colBn[ni] : cc;
          }
        }
      }
      // row-i reduction across the 16 column lanes (m15 bits)
#pragma unroll
      for (int off = 1; off <= 8; off <<= 1) {
        ull op = __shfl_xor(bp, off, 64);
        ull on = __shfl_xor(bn, off, 64);
        bp = bp > op ? bp : op;
        bn = bn < on ? bn : on;
      }
      if (m15 == 0) {
        if (bp != SENT_P) atomicMax(&best_pos[i], bp);
        if (bn != SENT_N) atomicMin(&best_neg[i], bn);
      }
    }
  }

  // col-j reduction across the 4 q lane-groups
#pragma unroll
  for (int ni = 0; ni < 4; ++ni) {
    ull cp = colBp[ni], cn = colBn[ni];
#pragma unroll
    for (int off = 16; off <= 32; off <<= 1) {
      ull op = __shfl_xor(cp, off, 64);
      ull on = __shfl_xor(cn, off, 64);
      cp = cp > op ? cp : op;
      cn = cn < on ? cn : on;
    }
    if (q == 0) {
      int j = jbase + wn * 64 + ni * 16 + m15;
      if (cp != SENT_P) atomicMax(&best_pos[j], cp);
      if (cn != SENT_N) atomicMin(&best_neg[j], cn);
    }
  }
}

// ---------------- loss + finalize in one single-block kernel ----------------
__global__ void k_loss_final(const ull* __restrict__ best_pos,
                             const ull* __restrict__ best_neg,
                             const float* __restrict__ rs,
                             float* __restrict__ out) {
  float per = 0.0f;
  int v = 0;
  for (int i = threadIdx.x; i < B; i += 1024) {
    ull bp = best_pos[i], bn = best_neg[i];
    if (bp != SENT_P && bn != SENT_N) {
      unsigned pRaw = ~(unsigned)bp;
      unsigned nRaw = (unsigned)bn;
      int pi = pRaw < (unsigned)B ? (int)pRaw : 0;
      int ni = nRaw < (unsigned)B ? (int)nRaw : 0;
      float distp = __uint_as_float((unsigned)(bp >> 32));
      float distn = __uint_as_float((unsigned)(bn >> 32));
      float ri = rs[i];
      const float e = 1e-6f, de2 = (float)D * 1e-12f;
      float dp2 = distp * distp + 2.0f * e * (ri - rs[pi]) + de2;
      float dn2 = distn * distn + 2.0f * e * (ri - rs[ni]) + de2;
      float dp = sqrtf(fmaxf(dp2, 0.0f));
      float dn = sqrtf(fmaxf(dn2, 0.0f));
      per += fmaxf(dp - dn + 0.3f, 0.0f);
      v += 1;
    }
  }
  for (int off = 32; off; off >>= 1) {
    per += __shfl_down(per, off, 64);
    v   += __shfl_down(v, off, 64);
  }
  __shared__ float pps[16];
  __shared__ int pvs[16];
  int lane = threadIdx.x & 63, wave = threadIdx.x >> 6;
  if (lane == 0) { pps[wave] = per; pvs[wave] = v; }
  __syncthreads();
  if (threadIdx.x == 0) {
    float t = 0.f;
    int cv = 0;
#pragma unroll
    for (int w = 0; w < 16; ++w) { t += pps[w]; cv += pvs[w]; }
    out[0] = cv > 0 ? t / (float)cv : 0.0f;
  }
}

// ---------------- launch -----------------------------------------------------
extern "C" void kernel_launch(void* const* d_in, const int* in_sizes, int n_in,
                              void* d_out, int out_size, void* d_ws, size_t ws_size,
                              hipStream_t stream) {
  const float* emb = (const float*)d_in[0];
  const int* labels = (const int*)d_in[1];
  float* out = (float*)d_out;
  char* ws = (char*)d_ws;

  const size_t off_embq = 0;
  const size_t off_sq   = off_embq + (size_t)B * D;       // 8 MiB
  const size_t off_rs   = off_sq + (size_t)B * 4;
  const size_t off_bp   = off_rs + (size_t)B * 4;
  const size_t off_bn   = off_bp + (size_t)B * 8;

  unsigned char* embq = (unsigned char*)(ws + off_embq);
  float* sq   = (float*)(ws + off_sq);
  float* rs   = (float*)(ws + off_rs);
  ull* bp     = (ull*)(ws + off_bp);
  ull* bn     = (ull*)(ws + off_bn);

  hipLaunchKernelGGL(k_convert_sq, dim3(B), dim3(256), 0, stream,
                     emb, embq, sq, rs, bp, bn);
  hipLaunchKernelGGL(k_gemm_select, dim3(1056), dim3(256), 0, stream,
                     embq, sq, labels, bp, bn);
  hipLaunchKernelGGL(k_loss_final, dim3(1), dim3(1024), 0, stream,
                     bp, bn, rs, out);
}